// Round 6
// baseline (185.358 us; speedup 1.0000x reference)
//
#include <hip/hip_runtime.h>

#define A_N 8400
#define B_N 32
#define NGT 64
#define NC  80
#define BA  (B_N * A_N)
#define NCOL (B_N * NGT)

typedef float f4 __attribute__((ext_vector_type(4)));

// ---------------------------------------------------------------------------
// Init: zero per-column counters + per-batch min/max. (fg now lives in bit 0
// of the per-anchor record written unconditionally by k_pairs -- no 1MB zero.)
// ---------------------------------------------------------------------------
__global__ __launch_bounds__(256) void k_init(int* __restrict__ cnts,
                                              unsigned* __restrict__ mn_g,
                                              unsigned* __restrict__ mx_g) {
  int tid = threadIdx.x;
  for (int i = tid; i < NCOL; i += 256) cnts[i] = 0;
  if (tid < B_N) {
    mn_g[tid] = __float_as_uint(1e30f);
    mx_g[tid] = 0u;  // +0.0f bits; am_max >= 0 always
  }
}

// ---------------------------------------------------------------------------
// Pass 1: block = 256 anchors of one batch.
// Phase 1 (branch-light, register-only): push (anchor,gt) iff in-box AND the
// predicted box overlaps the gt (iw>0 && ih>0). Pairs failing either have
// v == +0.0 exactly -> zero effect on list/argmax (round-6 insight: shrinks
// the expensive drain ~23x, from ~344k in-box to ~15k overlap pairs).
// Phase 2: cooperative drain -- scattered pd_s gathers with full MLP, then
// amf (bit-identical expression to rounds 1-5, contract off, verified
// absmax 0.0). Push to per-column lists + LDS atomicMax argmax on
// key = (vbits<<32)|((63-n)<<1)  (max v, tie -> min n; bit 0 free for fg).
// Final: per-anchor packed record -> recs[].
// ---------------------------------------------------------------------------
__global__ __launch_bounds__(256) void k_pairs(
    const float* __restrict__ pd_s, const float* __restrict__ pd_b,
    const float* __restrict__ anc, const int* __restrict__ gt_l,
    const float* __restrict__ gt_b, const int* __restrict__ mgt,
    unsigned long long* __restrict__ lists, int* __restrict__ cnts, int cap,
    unsigned long long* __restrict__ recs) {
#pragma clang fp contract(off)
  int b = blockIdx.y, tid = threadIdx.x;
  int a0 = blockIdx.x * 256, a = a0 + tid;
  bool av = a < A_N;

  __shared__ float4 gb_s[NGT];
  __shared__ int lab_s[NGT];
  __shared__ float4 pb_s[256];
  __shared__ unsigned long long key_s[256];
  __shared__ unsigned short wl[256 * 32];  // exact worst case per 32-gt chunk
  __shared__ int wl_cnt;
  __shared__ int cnt_sh;

  if (tid < NGT) {
    gb_s[tid] = ((const float4*)gt_b)[b * NGT + tid];
    lab_s[tid] = gt_l[b * NGT + tid];
    unsigned long long m = __ballot(mgt[b * NGT + tid] != 0);  // prefix mask
    if (tid == 0) cnt_sh = __popcll(m);
  }
  float4 pb = av ? ((const float4*)pd_b)[(size_t)b * A_N + a]
                 : make_float4(0.f, 0.f, 0.f, 0.f);
  float2 ap = av ? ((const float2*)anc)[a] : make_float2(-1e30f, -1e30f);
  pb_s[tid] = pb;
  key_s[tid] = (unsigned long long)(63 << 1);  // (v=0, n=0, fg=0) default
  if (tid == 0) wl_cnt = 0;
  __syncthreads();
  int cnt = cnt_sh;

  for (int g0 = 0; g0 < cnt; g0 += 32) {
    int ge = (g0 + 32 < cnt) ? g0 + 32 : cnt;
    // phase 1: in-box AND pred-overlap test (register-only, ~0.04% pass)
    if (av) {
      for (int n = g0; n < ge; n++) {
        float4 gb = gb_s[n];
        float mn = fminf(fminf(ap.x - gb.x, ap.y - gb.y),
                         fminf(gb.z - ap.x, gb.w - ap.y));
        float iwr = fminf(gb.z, pb.z) - fmaxf(gb.x, pb.x);
        float ihr = fminf(gb.w, pb.w) - fmaxf(gb.y, pb.y);
        if (mn > 0.0f && iwr > 0.0f && ihr > 0.0f) {
          int p = atomicAdd(&wl_cnt, 1);
          wl[p] = (unsigned short)((tid << 6) | (n & 63));
        }
      }
    }
    __syncthreads();
    int m = wl_cnt;
    // phase 2: drain (~14 items/block typical) -- gathers with full MLP
    for (int i = tid; i < m; i += 256) {
      int e = wl[i];
      int al = e >> 6, n = e & 63;
      int ag = a0 + al;
      float4 gb = gb_s[n];
      float4 pbl = pb_s[al];
      float iw = fmaxf(fminf(gb.z, pbl.z) - fmaxf(gb.x, pbl.x), 0.0f);
      float ih = fmaxf(fminf(gb.w, pbl.w) - fmaxf(gb.y, pbl.y), 0.0f);
      float inter = iw * ih;
      float w1 = gb.z - gb.x, h1 = (gb.w - gb.y) + 1e-16f;
      float w2 = pbl.z - pbl.x, h2 = (pbl.w - pbl.y) + 1e-16f;
      float uni = ((w1 * h1 + w2 * h2) - inter) + 1e-16f;
      float iou = inter / uni;
      float sc = pd_s[((size_t)b * A_N + ag) * NC + (size_t)lab_s[n]];
      float v = sqrtf(sc) * powf(iou, 6.0f);
      if (v > 0.0f) {
        unsigned vb = __float_as_uint(v);
        int col = b * NGT + n;
        int pos = atomicAdd(&cnts[col], 1);
        if (pos < cap) {
          lists[(size_t)col * cap + pos] =
              ((unsigned long long)vb << 32) |
              (unsigned long long)(0xFFFFFFFFu - (unsigned)ag);
        }
        atomicMax(&key_s[al], ((unsigned long long)vb << 32) |
                                  (unsigned long long)((63 - n) << 1));
      }
    }
    __syncthreads();
    if (tid == 0) wl_cnt = 0;
    __syncthreads();
  }

  if (av) recs[(size_t)b * A_N + a] = key_s[tid];
}

// ---------------------------------------------------------------------------
// Pass 2: per (b, gt) column, one wave. Winners = top-10 by (v desc, a asc)
// over the full 8400 column (jax.lax.top_k stable semantics). Positives from
// the list; if P < 10 the remaining winners are the smallest-index
// zero-valued anchors -- provably all within indices [0,19) since P <= 9 --
// selected wave-parallel via ballot rank; only in-box ones become fg.
// fg = atomicOr bit 0 of the packed per-anchor record. Per-batch min/max
// folded block-locally -> exactly one atomicMin+atomicMax per block (r5 fix).
// ---------------------------------------------------------------------------
__global__ __launch_bounds__(64) void k_topk(
    const unsigned long long* __restrict__ lists, const int* __restrict__ cnts,
    int cap, const int* __restrict__ mgt, const float* __restrict__ anc,
    const float* __restrict__ gt_b, unsigned long long* __restrict__ recs,
    unsigned* __restrict__ mn_g, unsigned* __restrict__ mx_g) {
  int b = blockIdx.x, n = blockIdx.y, tid = threadIdx.x;
  if (mgt[b * NGT + n] == 0) return;
  int col = b * NGT + n;
  int P = cnts[col];
  if (P > cap) P = cap;
  const unsigned long long* list = lists + (size_t)col * cap;
  unsigned* recw = (unsigned*)recs;  // [2i]=low(fg|gt), [2i+1]=am_max bits

  const unsigned MN_ID = __float_as_uint(1e30f);
  unsigned loc_mn = MN_ID, loc_mx = 0u;  // am_max >= 0 -> uint order ok

  if (P >= 10) {
    // All 10 winners positive => in_gts guaranteed.
    unsigned long long top[10];
#pragma unroll
    for (int j = 0; j < 10; j++) top[j] = 0ull;
    for (int i = tid; i < P; i += 64) {
      unsigned long long key = list[i];
#pragma unroll
      for (int j = 0; j < 10; j++) {
        if (key > top[j]) { unsigned long long t = top[j]; top[j] = key; key = t; }
      }
    }
    for (int r = 0; r < 10; r++) {
      unsigned long long g = top[0];
#pragma unroll
      for (int off = 32; off >= 1; off >>= 1) {
        unsigned long long o = __shfl_xor(g, off, 64);
        g = (o > g) ? o : g;
      }
      if (top[0] == g) {  // unique keys -> exactly one lane pops
#pragma unroll
        for (int j = 0; j < 9; j++) top[j] = top[j + 1];
        top[9] = 0ull;
      }
      if (tid == r) {
        size_t idx = (size_t)b * A_N +
                     (size_t)(0xFFFFFFFFu - (unsigned)(g & 0xFFFFFFFFull));
        atomicOr(&recw[2 * idx], 1u);
        unsigned u = recw[2 * idx + 1];
        loc_mn = (u < loc_mn) ? u : loc_mn;
        loc_mx = (u > loc_mx) ? u : loc_mx;
      }
    }
  } else {
    // Positives all win (lanes 0..P-1).
    int my_a = -1;
    if (tid < P)
      my_a = (int)(0xFFFFFFFFu - (unsigned)(list[tid] & 0xFFFFFFFFull));
    if (tid < P) {
      size_t idx = (size_t)b * A_N + my_a;
      atomicOr(&recw[2 * idx], 1u);
      unsigned u = recw[2 * idx + 1];
      loc_mn = (u < loc_mn) ? u : loc_mn;
      loc_mx = (u > loc_mx) ? u : loc_mx;
    }
    // Zero-tie winners: first (10-P) anchor indices not in the positive set.
    // P <= 9 => all within [0,19).
    bool is_pos = false;
    for (int i = 0; i < P; i++) {
      int ai = __shfl(my_a, i, 64);
      is_pos |= (ai == tid);
    }
    bool cand = (tid < 19) && !is_pos;
    unsigned long long fm = __ballot(cand);
    int rank = __popcll(fm & ((1ull << tid) - 1ull));
    if (cand && rank < 10 - P) {
      float4 gb = ((const float4*)gt_b)[b * NGT + n];
      float2 ap = ((const float2*)anc)[tid];
      float mn = fminf(fminf(ap.x - gb.x, ap.y - gb.y),
                       fminf(gb.z - ap.x, gb.w - ap.y));
      if (mn > 0.0f) {  // zero winner consumes a slot; fg only if in_gts
        size_t idx = (size_t)b * A_N + tid;
        atomicOr(&recw[2 * idx], 1u);
        unsigned u = recw[2 * idx + 1];
        loc_mn = (u < loc_mn) ? u : loc_mn;
        loc_mx = (u > loc_mx) ? u : loc_mx;
      }
    }
  }

  // block-local fold -> one atomicMin + one atomicMax per block
#pragma unroll
  for (int off = 32; off >= 1; off >>= 1) {
    unsigned o1 = __shfl_xor(loc_mn, off, 64);
    loc_mn = (o1 < loc_mn) ? o1 : loc_mn;
    unsigned o2 = __shfl_xor(loc_mx, off, 64);
    loc_mx = (o2 > loc_mx) ? o2 : loc_mx;
  }
  if (tid == 0 && loc_mn != MN_ID) {
    atomicMin(&mn_g[b], loc_mn);
    atomicMax(&mx_g[b], loc_mx);
  }
}

// ---------------------------------------------------------------------------
// Output: t_labels, t_bboxes, fg per anchor + contiguous 80-class score block
// (80 KB/block, coalesced float4). Single packed-record read per anchor;
// nontemporal stores for the 92 MB streaming output.
// ---------------------------------------------------------------------------
__global__ __launch_bounds__(256) void k_out(
    const int* __restrict__ gt_l, const float* __restrict__ gt_b,
    const unsigned long long* __restrict__ recs,
    const unsigned* __restrict__ mn_g, const unsigned* __restrict__ mx_g,
    float* __restrict__ out) {
  int b = blockIdx.y;
  int tid = threadIdx.x;
  int a0 = blockIdx.x * 256;
  int a = a0 + tid;

  __shared__ int cls_s[256];
  __shared__ float norm_s[256];

  if (a < A_N) {
    size_t i = (size_t)b * A_N + a;
    unsigned long long rec = recs[i];
    bool fg = (rec & 1ull) != 0;
    int bi = 63 - (int)((rec >> 1) & 63ull);
    float amx = __uint_as_float((unsigned)(rec >> 32));
    float mn = __uint_as_float(mn_g[b]);
    float mx = __uint_as_float(mx_g[b]);
    float norm = (amx - mn) / ((mx - mn) + 1e-9f);
    int lab = gt_l[b * NGT + bi];

    __builtin_nontemporal_store(fg ? (float)lab : (float)NC, &out[i]);
    f4 bb;
    if (fg) {
      float4 t = ((const float4*)gt_b)[b * NGT + bi];
      bb.x = t.x; bb.y = t.y; bb.z = t.z; bb.w = t.w;
    } else {
      bb = (f4){0.f, 0.f, 0.f, 0.f};
    }
    __builtin_nontemporal_store(bb, &((f4*)(out + BA))[i]);
    __builtin_nontemporal_store(fg ? 1.0f : 0.0f, &out[(size_t)85 * BA + i]);
    cls_s[tid] = fg ? lab : -1;
    norm_s[tid] = fg ? norm : 0.0f;
  } else {
    cls_s[tid] = -1;
    norm_s[tid] = 0.0f;
  }
  __syncthreads();

  int nA = A_N - a0;
  if (nA > 256) nA = 256;
  f4* dst = (f4*)(out + (size_t)5 * BA + ((size_t)b * A_N + a0) * NC);
  int nvec = nA * (NC / 4);
  for (int t = tid; t < nvec; t += 256) {
    int al = t / (NC / 4);
    int c0 = (t - al * (NC / 4)) * 4;
    int cls = cls_s[al];
    float nv = norm_s[al];
    f4 r;
    r.x = (c0 == cls) ? nv : 0.0f;
    r.y = (c0 + 1 == cls) ? nv : 0.0f;
    r.z = (c0 + 2 == cls) ? nv : 0.0f;
    r.w = (c0 + 3 == cls) ? nv : 0.0f;
    __builtin_nontemporal_store(r, &dst[t]);
  }
}

extern "C" void kernel_launch(void* const* d_in, const int* in_sizes, int n_in,
                              void* d_out, int out_size, void* d_ws,
                              size_t ws_size, hipStream_t stream) {
  const float* pd_s = (const float*)d_in[0];   // (B, A, 80)
  const float* pd_b = (const float*)d_in[1];   // (B, A, 4)
  const float* anc  = (const float*)d_in[2];   // (A, 2)
  const int*   gt_l = (const int*)d_in[3];     // (B, 64, 1)
  const float* gt_b = (const float*)d_in[4];   // (B, 64, 4)
  const int*   mgt  = (const int*)d_in[5];     // (B, 64, 1)

  float* out = (float*)d_out;
  char* ws = (char*)d_ws;

  // recs (8 B/anchor) + cnts + mn/mx at the end; per-column lists take the
  // rest of the workspace.
  const size_t REC_BYTES = (size_t)BA * 8;
  size_t small_bytes = REC_BYTES + (size_t)NCOL * 4 + 256;
  size_t avail = (ws_size > small_bytes) ? (ws_size - small_bytes) : 0;
  int cap = (int)(avail / ((size_t)NCOL * 8));
  if (cap > 4096) cap = 4096;  // v>0 anchors/col is O(10-100) with this data
  if (cap < 1) cap = 1;

  unsigned long long* lists = (unsigned long long*)ws;
  char* sb = ws + (size_t)NCOL * 8 * cap;
  unsigned long long* recs = (unsigned long long*)sb;
  int*      cnts = (int*)(sb + REC_BYTES);
  unsigned* mn_g = (unsigned*)(sb + REC_BYTES + (size_t)NCOL * 4);
  unsigned* mx_g = mn_g + B_N;

  dim3 g2((A_N + 255) / 256, B_N);
  k_init<<<1, 256, 0, stream>>>(cnts, mn_g, mx_g);
  k_pairs<<<g2, 256, 0, stream>>>(pd_s, pd_b, anc, gt_l, gt_b, mgt, lists,
                                  cnts, cap, recs);
  k_topk<<<dim3(B_N, NGT), 64, 0, stream>>>(lists, cnts, cap, mgt, anc, gt_b,
                                            recs, mn_g, mx_g);
  k_out<<<g2, 256, 0, stream>>>(gt_l, gt_b, recs, mn_g, mx_g, out);
}

// Round 7
// 182.909 us; speedup vs baseline: 1.0134x; 1.0134x over previous
//
#include <hip/hip_runtime.h>

#define A_N 8400
#define B_N 32
#define NGT 64
#define NC  80
#define BA  (B_N * A_N)
#define NCOL (B_N * NGT)

typedef float f4 __attribute__((ext_vector_type(4)));

// ---------------------------------------------------------------------------
// Init: zero per-column counters + per-batch min/max.
// ---------------------------------------------------------------------------
__global__ __launch_bounds__(256) void k_init(int* __restrict__ cnts,
                                              unsigned* __restrict__ mn_g,
                                              unsigned* __restrict__ mx_g) {
  int tid = threadIdx.x;
  for (int i = tid; i < NCOL; i += 256) cnts[i] = 0;
  if (tid < B_N) {
    mn_g[tid] = __float_as_uint(1e30f);
    mx_g[tid] = 0u;  // +0.0f bits; am_max >= 0 always
  }
}

// ---------------------------------------------------------------------------
// Pass 1: block = 256 anchors of one batch. ROUND 7: single-pass worklist --
// one phase-1 sweep over ALL gts (cheap register-only in-box AND pred-overlap
// test; failures have v == +0.0 exactly), ONE barrier, one cooperative drain,
// one barrier. (r6 had 6 barriers per 32-gt chunk; phases were each tiny, the
// barriers were not.)
// Drain: scattered pd_s gathers with full MLP + amf (bit-identical expression
// to rounds 1-6, contract off, verified absmax 0.0). Results: per-column
// candidate lists + per-anchor argmax via LDS atomicMax on
// key = (vbits<<32)|((63-n)<<1) (max v, tie -> min n; bit 0 reserved for fg).
// ---------------------------------------------------------------------------
__global__ __launch_bounds__(256) void k_pairs(
    const float* __restrict__ pd_s, const float* __restrict__ pd_b,
    const float* __restrict__ anc, const int* __restrict__ gt_l,
    const float* __restrict__ gt_b, const int* __restrict__ mgt,
    unsigned long long* __restrict__ lists, int* __restrict__ cnts, int cap,
    unsigned long long* __restrict__ recs) {
#pragma clang fp contract(off)
  int b = blockIdx.y, tid = threadIdx.x;
  int a0 = blockIdx.x * 256, a = a0 + tid;
  bool av = a < A_N;

  __shared__ float4 gb_s[NGT];
  __shared__ int lab_s[NGT];
  __shared__ float4 pb_s[256];
  __shared__ unsigned long long key_s[256];
  __shared__ unsigned short wl[256 * 64];  // 32 KB: exact worst case (all pairs)
  __shared__ int wl_cnt;
  __shared__ int cnt_sh;

  if (tid < NGT) {
    gb_s[tid] = ((const float4*)gt_b)[b * NGT + tid];
    lab_s[tid] = gt_l[b * NGT + tid];
    unsigned long long m = __ballot(mgt[b * NGT + tid] != 0);  // prefix mask
    if (tid == 0) cnt_sh = __popcll(m);
  }
  float4 pb = av ? ((const float4*)pd_b)[(size_t)b * A_N + a]
                 : make_float4(0.f, 0.f, 0.f, 0.f);
  float2 ap = av ? ((const float2*)anc)[a] : make_float2(-1e30f, -1e30f);
  pb_s[tid] = pb;
  key_s[tid] = (unsigned long long)(63 << 1);  // (v=0, n=0, fg=0) default
  if (tid == 0) wl_cnt = 0;
  __syncthreads();
  int cnt = cnt_sh;

  // phase 1: one sweep over all valid gts (~0.04% pairs pass both tests)
  if (av) {
    for (int n = 0; n < cnt; n++) {
      float4 gb = gb_s[n];
      float mn = fminf(fminf(ap.x - gb.x, ap.y - gb.y),
                       fminf(gb.z - ap.x, gb.w - ap.y));
      float iwr = fminf(gb.z, pb.z) - fmaxf(gb.x, pb.x);
      float ihr = fminf(gb.w, pb.w) - fmaxf(gb.y, pb.y);
      if (mn > 0.0f && iwr > 0.0f && ihr > 0.0f) {
        int p = atomicAdd(&wl_cnt, 1);
        wl[p] = (unsigned short)((tid << 6) | n);
      }
    }
  }
  __syncthreads();
  int m = wl_cnt;

  // phase 2: cooperative drain (~14 items/block typical), full MLP gathers
  for (int i = tid; i < m; i += 256) {
    int e = wl[i];
    int al = e >> 6, n = e & 63;
    int ag = a0 + al;
    float4 gb = gb_s[n];
    float4 pbl = pb_s[al];
    float iw = fmaxf(fminf(gb.z, pbl.z) - fmaxf(gb.x, pbl.x), 0.0f);
    float ih = fmaxf(fminf(gb.w, pbl.w) - fmaxf(gb.y, pbl.y), 0.0f);
    float inter = iw * ih;
    float w1 = gb.z - gb.x, h1 = (gb.w - gb.y) + 1e-16f;
    float w2 = pbl.z - pbl.x, h2 = (pbl.w - pbl.y) + 1e-16f;
    float uni = ((w1 * h1 + w2 * h2) - inter) + 1e-16f;
    float iou = inter / uni;
    float sc = pd_s[((size_t)b * A_N + ag) * NC + (size_t)lab_s[n]];
    float v = sqrtf(sc) * powf(iou, 6.0f);
    if (v > 0.0f) {
      unsigned vb = __float_as_uint(v);
      int col = b * NGT + n;
      int pos = atomicAdd(&cnts[col], 1);
      if (pos < cap) {
        lists[(size_t)col * cap + pos] =
            ((unsigned long long)vb << 32) |
            (unsigned long long)(0xFFFFFFFFu - (unsigned)ag);
      }
      atomicMax(&key_s[al], ((unsigned long long)vb << 32) |
                                (unsigned long long)((63 - n) << 1));
    }
  }
  __syncthreads();

  if (av) recs[(size_t)b * A_N + a] = key_s[tid];
}

// ---------------------------------------------------------------------------
// Pass 2: per (b, gt) column, one wave. Winners = top-10 by (v desc, a asc)
// over the full 8400 column (jax.lax.top_k stable semantics). Positives from
// the list; if P < 10 the remaining winners are the smallest-index
// zero-valued anchors (all within [0,19) since P <= 9), selected
// wave-parallel via ballot rank; only in-box ones become fg.
// fg = atomicOr bit 0 of the packed per-anchor record. Per-batch min/max
// folded block-locally -> one atomicMin+atomicMax per block (r5 fix).
// ---------------------------------------------------------------------------
__global__ __launch_bounds__(64) void k_topk(
    const unsigned long long* __restrict__ lists, const int* __restrict__ cnts,
    int cap, const int* __restrict__ mgt, const float* __restrict__ anc,
    const float* __restrict__ gt_b, unsigned long long* __restrict__ recs,
    unsigned* __restrict__ mn_g, unsigned* __restrict__ mx_g) {
  int b = blockIdx.x, n = blockIdx.y, tid = threadIdx.x;
  if (mgt[b * NGT + n] == 0) return;
  int col = b * NGT + n;
  int P = cnts[col];
  if (P > cap) P = cap;
  const unsigned long long* list = lists + (size_t)col * cap;
  unsigned* recw = (unsigned*)recs;  // [2i]=low(fg|gt), [2i+1]=am_max bits

  const unsigned MN_ID = __float_as_uint(1e30f);
  unsigned loc_mn = MN_ID, loc_mx = 0u;  // am_max >= 0 -> uint order ok

  if (P >= 10) {
    // All 10 winners positive => in_gts guaranteed.
    unsigned long long top[10];
#pragma unroll
    for (int j = 0; j < 10; j++) top[j] = 0ull;
    for (int i = tid; i < P; i += 64) {
      unsigned long long key = list[i];
#pragma unroll
      for (int j = 0; j < 10; j++) {
        if (key > top[j]) { unsigned long long t = top[j]; top[j] = key; key = t; }
      }
    }
    for (int r = 0; r < 10; r++) {
      unsigned long long g = top[0];
#pragma unroll
      for (int off = 32; off >= 1; off >>= 1) {
        unsigned long long o = __shfl_xor(g, off, 64);
        g = (o > g) ? o : g;
      }
      if (top[0] == g) {  // unique keys -> exactly one lane pops
#pragma unroll
        for (int j = 0; j < 9; j++) top[j] = top[j + 1];
        top[9] = 0ull;
      }
      if (tid == r) {
        size_t idx = (size_t)b * A_N +
                     (size_t)(0xFFFFFFFFu - (unsigned)(g & 0xFFFFFFFFull));
        atomicOr(&recw[2 * idx], 1u);
        unsigned u = recw[2 * idx + 1];
        loc_mn = (u < loc_mn) ? u : loc_mn;
        loc_mx = (u > loc_mx) ? u : loc_mx;
      }
    }
  } else {
    // Positives all win (lanes 0..P-1).
    int my_a = -1;
    if (tid < P)
      my_a = (int)(0xFFFFFFFFu - (unsigned)(list[tid] & 0xFFFFFFFFull));
    if (tid < P) {
      size_t idx = (size_t)b * A_N + my_a;
      atomicOr(&recw[2 * idx], 1u);
      unsigned u = recw[2 * idx + 1];
      loc_mn = (u < loc_mn) ? u : loc_mn;
      loc_mx = (u > loc_mx) ? u : loc_mx;
    }
    // Zero-tie winners: first (10-P) anchor indices not in the positive set.
    bool is_pos = false;
    for (int i = 0; i < P; i++) {
      int ai = __shfl(my_a, i, 64);
      is_pos |= (ai == tid);
    }
    bool cand = (tid < 19) && !is_pos;
    unsigned long long fm = __ballot(cand);
    int rank = __popcll(fm & ((1ull << tid) - 1ull));
    if (cand && rank < 10 - P) {
      float4 gb = ((const float4*)gt_b)[b * NGT + n];
      float2 ap = ((const float2*)anc)[tid];
      float mn = fminf(fminf(ap.x - gb.x, ap.y - gb.y),
                       fminf(gb.z - ap.x, gb.w - ap.y));
      if (mn > 0.0f) {  // zero winner consumes a slot; fg only if in_gts
        size_t idx = (size_t)b * A_N + tid;
        atomicOr(&recw[2 * idx], 1u);
        unsigned u = recw[2 * idx + 1];
        loc_mn = (u < loc_mn) ? u : loc_mn;
        loc_mx = (u > loc_mx) ? u : loc_mx;
      }
    }
  }

  // block-local fold -> one atomicMin + one atomicMax per block
#pragma unroll
  for (int off = 32; off >= 1; off >>= 1) {
    unsigned o1 = __shfl_xor(loc_mn, off, 64);
    loc_mn = (o1 < loc_mn) ? o1 : loc_mn;
    unsigned o2 = __shfl_xor(loc_mx, off, 64);
    loc_mx = (o2 > loc_mx) ? o2 : loc_mx;
  }
  if (tid == 0 && loc_mn != MN_ID) {
    atomicMin(&mn_g[b], loc_mn);
    atomicMax(&mx_g[b], loc_mx);
  }
}

// ---------------------------------------------------------------------------
// ROUND 7 finalize: bboxes/scores/fg regions are pre-zeroed by hipMemsetAsync
// (91.4 MB at the fill kernels' proven ~6.5 TB/s). This kernel writes only:
// the dense label plane (1 MB) + sparse per-fg-anchor data (~2k anchors:
// bbox 16 B, fg 4 B, ONE score scalar -- t_scores is one-hot * norm).
// ---------------------------------------------------------------------------
__global__ __launch_bounds__(256) void k_fin(
    const int* __restrict__ gt_l, const float* __restrict__ gt_b,
    const unsigned long long* __restrict__ recs,
    const unsigned* __restrict__ mn_g, const unsigned* __restrict__ mx_g,
    float* __restrict__ out) {
  int b = blockIdx.y;
  int a = blockIdx.x * 256 + threadIdx.x;
  if (a >= A_N) return;
  size_t i = (size_t)b * A_N + a;
  unsigned long long rec = recs[i];
  bool fg = (rec & 1ull) != 0;
  int bi = 63 - (int)((rec >> 1) & 63ull);
  int lab = gt_l[b * NGT + bi];

  out[i] = fg ? (float)lab : (float)NC;  // t_labels (dense)
  if (fg) {
    float amx = __uint_as_float((unsigned)(rec >> 32));
    float mn = __uint_as_float(mn_g[b]);
    float mx = __uint_as_float(mx_g[b]);
    float norm = (amx - mn) / ((mx - mn) + 1e-9f);
    float4 t = ((const float4*)gt_b)[b * NGT + bi];
    f4 bb = {t.x, t.y, t.z, t.w};
    ((f4*)(out + BA))[i] = bb;                          // t_bboxes
    out[(size_t)85 * BA + i] = 1.0f;                    // fg
    out[(size_t)5 * BA + i * NC + (size_t)lab] = norm;  // one-hot score
  }
}

extern "C" void kernel_launch(void* const* d_in, const int* in_sizes, int n_in,
                              void* d_out, int out_size, void* d_ws,
                              size_t ws_size, hipStream_t stream) {
  const float* pd_s = (const float*)d_in[0];   // (B, A, 80)
  const float* pd_b = (const float*)d_in[1];   // (B, A, 4)
  const float* anc  = (const float*)d_in[2];   // (A, 2)
  const int*   gt_l = (const int*)d_in[3];     // (B, 64, 1)
  const float* gt_b = (const float*)d_in[4];   // (B, 64, 4)
  const int*   mgt  = (const int*)d_in[5];     // (B, 64, 1)

  float* out = (float*)d_out;
  char* ws = (char*)d_ws;

  const size_t REC_BYTES = (size_t)BA * 8;
  size_t small_bytes = REC_BYTES + (size_t)NCOL * 4 + 256;
  size_t avail = (ws_size > small_bytes) ? (ws_size - small_bytes) : 0;
  int cap = (int)(avail / ((size_t)NCOL * 8));
  if (cap > 4096) cap = 4096;
  if (cap < 1) cap = 1;

  unsigned long long* lists = (unsigned long long*)ws;
  char* sb = ws + (size_t)NCOL * 8 * cap;
  unsigned long long* recs = (unsigned long long*)sb;
  int*      cnts = (int*)(sb + REC_BYTES);
  unsigned* mn_g = (unsigned*)(sb + REC_BYTES + (size_t)NCOL * 4);
  unsigned* mx_g = mn_g + B_N;

  // Pre-zero bboxes+scores+fg regions [BA, 86*BA): 91.4 MB at fill-kernel BW.
  hipMemsetAsync(out + BA, 0, (size_t)85 * BA * 4, stream);

  dim3 g2((A_N + 255) / 256, B_N);
  k_init<<<1, 256, 0, stream>>>(cnts, mn_g, mx_g);
  k_pairs<<<g2, 256, 0, stream>>>(pd_s, pd_b, anc, gt_l, gt_b, mgt, lists,
                                  cnts, cap, recs);
  k_topk<<<dim3(B_N, NGT), 64, 0, stream>>>(lists, cnts, cap, mgt, anc, gt_b,
                                            recs, mn_g, mx_g);
  k_fin<<<g2, 256, 0, stream>>>(gt_l, gt_b, recs, mn_g, mx_g, out);
}